// Round 13
// baseline (386.109 us; speedup 1.0000x reference)
//
#include <hip/hip_runtime.h>
#include <cmath>

#define CNUM 512
#define DNUM 128
#define BNUM 4096
#define EPSV 1e-5f
#define GPBLK 72            // (4096 + 512) / 64 split-K partial blocks
#define NBLK 256

// ---- all intermediates in device globals ----
__device__ float g_counts[CNUM];
__device__ float g_mean[CNUM * DNUM];
__device__ float g_lp[CNUM];
__device__ float g_G[DNUM * DNUM];
__device__ float g_Gp[GPBLK * DNUM * DNUM];   // split-K partials, 4.7 MB
__device__ float g_P[DNUM * DNUM];
__device__ float g_Pm[CNUM * DNUM];
__device__ float g_r[CNUM];
__device__ float g_q[BNUM];
__device__ unsigned g_bars[8];                // monotonic arrive counters (never reset)

// Device-scope grid barrier: each call adds exactly NBLK to slot i, so
// target = (old & ~(NBLK-1)) + NBLK. Monotonic => safe across graph replays.
__device__ __forceinline__ void gridbar(int i) {
    __threadfence();                          // release: prior writes visible
    __syncthreads();
    if (threadIdx.x == 0) {
        unsigned old = atomicAdd(&g_bars[i], 1u);
        unsigned target = (old & ~(unsigned)(NBLK - 1)) + (unsigned)NBLK;
        while (atomicAdd(&g_bars[i], 0u) < target) __builtin_amdgcn_s_sleep(2);
    }
    __syncthreads();
    __threadfence();                          // acquire: see others' writes
}

// LDS overlay: phases separated by gridbar, lifetimes never overlap.
union SmemAll {
    struct { float cnt[CNUM]; float acc[CNUM][8]; } cs;      // 18 KB
    struct { float xs[64][132]; float ws[64]; } gp;          // 34 KB
    struct { float colu[2][128]; float rowu[2][128]; float dshs[2]; } gj; // 2 KB
    struct { float xs[64][132]; float part[64][33]; } xp;    // 42 KB
    struct { float zs[64][65]; float ps[64][65]; } ou;       // 33 KB
};

__global__ __launch_bounds__(256) void k_all(const float* __restrict__ z, const int* __restrict__ y,
                                             float* __restrict__ out, float logtot, float invtot2) {
    __shared__ SmemAll sm;
    const int t = threadIdx.x;
    const int bi = blockIdx.x;

    // ================= phase 0: class sums + counts + mean + logprior =================
    if (bi < 17) {
        float* cnt = sm.cs.cnt;
        cnt[t] = 0.0f; cnt[t + 256] = 0.0f;
        __syncthreads();
        #pragma unroll
        for (int i = 0; i < 16; ++i) atomicAdd(&cnt[y[i * 256 + t]], 1.0f);
        __syncthreads();
        if (bi < 16) {
            #pragma unroll
            for (int v = 0; v < 16; ++v) {
                int idx = t + v * 256;
                sm.cs.acc[idx >> 3][idx & 7] = 0.0f;
            }
            __syncthreads();
            const int d0 = bi * 8;
            #pragma unroll
            for (int i = 0; i < 16; ++i) {
                int s = i * 256 + t;
                int yy = y[s];
                const float4* zp = (const float4*)(z + (size_t)s * DNUM + d0);
                float4 a = zp[0], b = zp[1];
                float* dst = &sm.cs.acc[yy][0];
                atomicAdd(dst + 0, a.x); atomicAdd(dst + 1, a.y);
                atomicAdd(dst + 2, a.z); atomicAdd(dst + 3, a.w);
                atomicAdd(dst + 4, b.x); atomicAdd(dst + 5, b.y);
                atomicAdd(dst + 6, b.z); atomicAdd(dst + 7, b.w);
            }
            __syncthreads();
            #pragma unroll
            for (int v = 0; v < 2; ++v) {
                int c = t + v * 256;
                float inv = 1.0f / (cnt[c] + EPSV);
                float4 a0 = *(float4*)&sm.cs.acc[c][0];
                float4 a1 = *(float4*)&sm.cs.acc[c][4];
                *(float4*)&g_mean[(size_t)c * DNUM + d0]     = make_float4(a0.x * inv, a0.y * inv, a0.z * inv, a0.w * inv);
                *(float4*)&g_mean[(size_t)c * DNUM + d0 + 4] = make_float4(a1.x * inv, a1.y * inv, a1.z * inv, a1.w * inv);
            }
        } else {
            #pragma unroll
            for (int v = 0; v < 2; ++v) {
                int c = t + v * 256;
                g_counts[c] = cnt[c];
                g_lp[c] = logf(cnt[c] + EPSV) - logtot;
            }
        }
    }
    gridbar(0);

    // ================= phase 1: G split-K partials =================
    if (bi < GPBLK) {
        const int R0 = bi * 64;
        #pragma unroll
        for (int v = 0; v < 8; ++v) {
            int idx = t + v * 256;
            int r = idx >> 5, f4 = idx & 31;
            int row = R0 + r;
            float4 val;
            if (row < BNUM) {
                val = ((const float4*)z)[(size_t)row * 32 + f4];
                if (f4 == 0) sm.gp.ws[r] = 1.0f;
            } else {
                int c = row - BNUM;
                val = ((const float4*)g_mean)[(size_t)c * 32 + f4];
                if (f4 == 0) sm.gp.ws[r] = -(g_counts[c] + 2.0f * EPSV);
            }
            *(float4*)&sm.gp.xs[r][f4 * 4] = val;
        }
        __syncthreads();
        const int tx = t & 15, ty = t >> 4;
        float acc[8][8] = {};
        #pragma unroll
        for (int s = 0; s < 64; ++s) {
            const float4* pa = (const float4*)&sm.gp.xs[s][ty * 8];
            const float4* pb = (const float4*)&sm.gp.xs[s][tx * 8];
            float w = sm.gp.ws[s];
            float4 t0 = pa[0], t1 = pa[1];
            float4 u0 = pb[0], u1 = pb[1];
            float va[8] = {w * t0.x, w * t0.y, w * t0.z, w * t0.w, w * t1.x, w * t1.y, w * t1.z, w * t1.w};
            float vb[8] = {u0.x, u0.y, u0.z, u0.w, u1.x, u1.y, u1.z, u1.w};
            #pragma unroll
            for (int i = 0; i < 8; ++i)
                #pragma unroll
                for (int j = 0; j < 8; ++j)
                    acc[i][j] += va[i] * vb[j];
        }
        float* gp = g_Gp + (size_t)bi * DNUM * DNUM;
        #pragma unroll
        for (int i = 0; i < 8; ++i) {
            *(float4*)(gp + (size_t)(ty * 8 + i) * DNUM + tx * 8)     = make_float4(acc[i][0], acc[i][1], acc[i][2], acc[i][3]);
            *(float4*)(gp + (size_t)(ty * 8 + i) * DNUM + tx * 8 + 4) = make_float4(acc[i][4], acc[i][5], acc[i][6], acc[i][7]);
        }
    }
    gridbar(1);

    // ================= phase 2: reduce 72 partials -> g_G =================
    if (bi < 64) {
        int idx = bi * 256 + t;
        float s = 0.0f;
        #pragma unroll
        for (int p = 0; p < GPBLK; ++p) s += g_Gp[(size_t)p * DNUM * DNUM + idx];
        g_G[idx] = s;
    }
    gridbar(2);

    // ================= phase 3: register-tile GJ inverse (block 0 only) =================
    if (bi == 0) {
        float (*colu)[128] = sm.gj.colu;
        float (*rowu)[128] = sm.gj.rowu;
        float* dshs = sm.gj.dshs;
        const int tx = t & 15, ty = t >> 4;
        const int R = ty * 8, Cc = tx * 8;
        float a[8][8];
        #pragma unroll
        for (int i = 0; i < 8; ++i)
            #pragma unroll
            for (int j = 0; j < 8; ++j) {
                int gi = R + i, gj = Cc + j;
                float v = (g_G[gi * DNUM + gj] + g_G[gj * DNUM + gi]) * invtot2;
                if (gi == gj) v += EPSV;
                a[i][j] = v;
            }
        if (tx == 0) {
            #pragma unroll
            for (int i = 0; i < 8; ++i) { int gi = R + i; colu[0][gi] = (gi == 0) ? 0.f : a[i][0]; }
        }
        if (ty == 0) {
            #pragma unroll
            for (int j = 0; j < 8; ++j) { int gj = Cc + j; rowu[0][gj] = (gj == 0) ? 0.f : a[0][j]; }
        }
        if (tx == 0 && ty == 0) dshs[0] = 1.0f / a[0][0];
        __syncthreads();
        for (int kb = 0; kb < 16; ++kb) {
            #pragma unroll
            for (int ko = 0; ko < 8; ++ko) {
                const int k = kb * 8 + ko;
                const int buf = k & 1;
                const float d = dshs[buf];
                float4 c0 = *(const float4*)&colu[buf][R], c1 = *(const float4*)&colu[buf][R + 4];
                float4 r0 = *(const float4*)&rowu[buf][Cc], r1 = *(const float4*)&rowu[buf][Cc + 4];
                float cd[8] = {-d * c0.x, -d * c0.y, -d * c0.z, -d * c0.w,
                               -d * c1.x, -d * c1.y, -d * c1.z, -d * c1.w};
                float rr[8] = {r0.x, r0.y, r0.z, r0.w, r1.x, r1.y, r1.z, r1.w};
                #pragma unroll
                for (int i = 0; i < 8; ++i)
                    #pragma unroll
                    for (int j = 0; j < 8; ++j)
                        a[i][j] += cd[i] * rr[j];
                if (tx == kb) {
                    #pragma unroll
                    for (int i = 0; i < 8; ++i) { int gi = R + i; if (gi != k) a[i][ko] = cd[i]; }
                }
                if (ty == kb) {
                    #pragma unroll
                    for (int j = 0; j < 8; ++j) { int gj = Cc + j; if (gj != k) a[ko][j] *= d; }
                    if (tx == kb) a[ko][ko] = d;
                }
                if (k < 127) {
                    const int nb = buf ^ 1;
                    if (ko < 7) {
                        const int kn = k + 1;
                        if (tx == kb) {
                            #pragma unroll
                            for (int i = 0; i < 8; ++i) { int gi = R + i; colu[nb][gi] = (gi == kn) ? 0.f : a[i][ko + 1]; }
                        }
                        if (ty == kb) {
                            #pragma unroll
                            for (int j = 0; j < 8; ++j) { int gj = Cc + j; rowu[nb][gj] = (gj == kn) ? 0.f : a[ko + 1][j]; }
                        }
                        if (tx == kb && ty == kb) dshs[nb] = 1.0f / a[ko + 1][ko + 1];
                    } else {
                        const int kn = k + 1;
                        if (tx == kb + 1) {
                            #pragma unroll
                            for (int i = 0; i < 8; ++i) { int gi = R + i; colu[nb][gi] = (gi == kn) ? 0.f : a[i][0]; }
                        }
                        if (ty == kb + 1) {
                            #pragma unroll
                            for (int j = 0; j < 8; ++j) { int gj = Cc + j; rowu[nb][gj] = (gj == kn) ? 0.f : a[0][j]; }
                        }
                        if (tx == kb + 1 && ty == kb + 1) dshs[nb] = 1.0f / a[0][0];
                    }
                }
                __syncthreads();
            }
        }
        #pragma unroll
        for (int i = 0; i < 8; ++i) {
            *(float4*)(g_P + (size_t)(R + i) * DNUM + Cc)     = make_float4(a[i][0], a[i][1], a[i][2], a[i][3]);
            *(float4*)(g_P + (size_t)(R + i) * DNUM + Cc + 4) = make_float4(a[i][4], a[i][5], a[i][6], a[i][7]);
        }
    }
    gridbar(3);

    // ================= phase 4: X@P row-dots (Pm, r, q) =================
    if (bi < GPBLK) {
        const bool mmode = (bi < 8);
        const float* __restrict__ X = mmode ? (const float*)g_mean : z;
        const int row0 = mmode ? bi * 64 : (bi - 8) * 64;
        #pragma unroll
        for (int v = 0; v < 8; ++v) {
            int idx = t + v * 256;
            int r = idx >> 5, f4 = idx & 31;
            float4 val = ((const float4*)X)[(size_t)(row0 + r) * 32 + f4];
            *(float4*)&sm.xp.xs[r][f4 * 4] = val;
        }
        __syncthreads();
        int tx = t & 31, ty = t >> 5;
        float acc[8][4] = {};
        for (int e = 0; e < DNUM; ++e) {
            float4 pv = ((const float4*)g_P)[e * 32 + tx];
            #pragma unroll
            for (int i = 0; i < 8; ++i) {
                float xv = sm.xp.xs[ty * 8 + i][e];
                acc[i][0] += xv * pv.x; acc[i][1] += xv * pv.y;
                acc[i][2] += xv * pv.z; acc[i][3] += xv * pv.w;
            }
        }
        #pragma unroll
        for (int i = 0; i < 8; ++i) {
            int r = ty * 8 + i;
            if (mmode)
                *(float4*)&g_Pm[(size_t)(row0 + r) * DNUM + tx * 4] =
                    make_float4(acc[i][0], acc[i][1], acc[i][2], acc[i][3]);
            sm.xp.part[r][tx] = acc[i][0] * sm.xp.xs[r][tx * 4 + 0] + acc[i][1] * sm.xp.xs[r][tx * 4 + 1]
                              + acc[i][2] * sm.xp.xs[r][tx * 4 + 2] + acc[i][3] * sm.xp.xs[r][tx * 4 + 3];
        }
        __syncthreads();
        if (t < 64) {
            float s = 0.f;
            #pragma unroll
            for (int x = 0; x < 32; ++x) s += sm.xp.part[t][x];
            if (mmode) g_r[row0 + t] = s;
            else       g_q[row0 + t] = s;
        }
    }
    gridbar(4);

    // ================= phase 5: out, 2 tiles per block =================
    for (int rep = 0; rep < 2; ++rep) {
        const int tile = bi * 2 + rep;
        const int c0 = (tile & 7) * 64;
        const int m0 = (tile >> 3) * 64;
        const int tx = t & 15, ty = t >> 4;
        float acc[4][4] = {};
        for (int kc = 0; kc < 2; ++kc) {
            #pragma unroll
            for (int v = 0; v < 4; ++v) {
                int idx = t + v * 256;
                int r = idx >> 4, f4 = idx & 15;
                float4 zv = ((const float4*)z)[(size_t)(m0 + r) * 32 + kc * 16 + f4];
                sm.ou.zs[r][f4 * 4 + 0] = zv.x; sm.ou.zs[r][f4 * 4 + 1] = zv.y;
                sm.ou.zs[r][f4 * 4 + 2] = zv.z; sm.ou.zs[r][f4 * 4 + 3] = zv.w;
                float4 pv = ((const float4*)g_Pm)[(size_t)(c0 + r) * 32 + kc * 16 + f4];
                sm.ou.ps[r][f4 * 4 + 0] = pv.x; sm.ou.ps[r][f4 * 4 + 1] = pv.y;
                sm.ou.ps[r][f4 * 4 + 2] = pv.z; sm.ou.ps[r][f4 * 4 + 3] = pv.w;
            }
            __syncthreads();
            #pragma unroll 8
            for (int kk = 0; kk < 64; ++kk) {
                float za[4], pb[4];
                #pragma unroll
                for (int i = 0; i < 4; ++i) za[i] = sm.ou.zs[ty * 4 + i][kk];
                #pragma unroll
                for (int j = 0; j < 4; ++j) pb[j] = sm.ou.ps[tx * 4 + j][kk];
                #pragma unroll
                for (int i = 0; i < 4; ++i)
                    #pragma unroll
                    for (int j = 0; j < 4; ++j)
                        acc[i][j] += za[i] * pb[j];
            }
            __syncthreads();
        }
        int cbase = c0 + tx * 4;
        float4 lp4 = *(const float4*)(g_lp + cbase);
        float4 rv4 = *(const float4*)(g_r + cbase);
        #pragma unroll
        for (int i = 0; i < 4; ++i) {
            int row = m0 + ty * 4 + i;
            float qv = g_q[row];
            float4 o;
            o.x = acc[i][0] + lp4.x - 0.5f * (qv + rv4.x);
            o.y = acc[i][1] + lp4.y - 0.5f * (qv + rv4.y);
            o.z = acc[i][2] + lp4.z - 0.5f * (qv + rv4.z);
            o.w = acc[i][3] + lp4.w - 0.5f * (qv + rv4.w);
            *(float4*)&out[(size_t)row * CNUM + cbase] = o;
        }
    }
}

extern "C" void kernel_launch(void* const* d_in, const int* in_sizes, int n_in,
                              void* d_out, int out_size, void* d_ws, size_t ws_size,
                              hipStream_t stream) {
    const float* z = (const float*)d_in[0];
    const int* y = (const int*)d_in[1];
    float* out = (float*)d_out;
    const int B = in_sizes[0] / DNUM;                 // 4096
    const float total = (float)B + (float)CNUM * EPSV;
    const float logtot = logf(total);

    k_all<<<NBLK, 256, 0, stream>>>(z, y, out, logtot, 0.5f / total);
}

// Round 14
// 186.118 us; speedup vs baseline: 2.0745x; 2.0745x over previous
//
#include <hip/hip_runtime.h>
#include <cmath>

#define CNUM 512
#define DNUM 128
#define BNUM 4096
#define EPSV 1e-5f
#define GPBLK 72            // (4096 + 512) / 64 split-K partial blocks

// ---- all intermediates in device globals: no d_ws dependence at all ----
__device__ float g_counts[CNUM];
__device__ float g_mean[CNUM * DNUM];
__device__ float g_lp[CNUM];
__device__ float g_G[DNUM * DNUM];
__device__ float g_Gp[GPBLK * DNUM * DNUM];   // split-K partials, 4.7 MB
__device__ float g_P[DNUM * DNUM];
__device__ float g_Pm[CNUM * DNUM];
__device__ float g_r[CNUM];
__device__ float g_q[BNUM];

// ---- class sums + counts + mean + logprior, no global atomics ----
// v2: 32 blocks own 4-dim slices (d0 = bi*4); LDS layout acc[c*5+d] --
// stride 5 is coprime with 32 banks so class bases spread over ALL banks
// (old [c][8] layout hit only 4 banks -> ~16-way conflicts, 2.7M total).
// Block 32 writes counts + logprior.
__global__ __launch_bounds__(256) void k_csum(const float* __restrict__ z, const int* __restrict__ y,
                                              float logtot) {
    const int t = threadIdx.x;
    const int bi = blockIdx.x;
    __shared__ float cnt[CNUM];
    cnt[t] = 0.0f; cnt[t + 256] = 0.0f;
    __syncthreads();
    #pragma unroll
    for (int i = 0; i < 16; ++i) atomicAdd(&cnt[y[i * 256 + t]], 1.0f);
    __syncthreads();
    if (bi < 32) {
        __shared__ float acc[CNUM * 5];       // 10 KB, stride-5 padded
        #pragma unroll
        for (int v = 0; v < 10; ++v) acc[t + v * 256] = 0.0f;
        __syncthreads();
        const int d0 = bi * 4;
        #pragma unroll
        for (int i = 0; i < 16; ++i) {
            int s = i * 256 + t;
            int yy = y[s];
            float4 a = *(const float4*)(z + (size_t)s * DNUM + d0);
            float* dst = &acc[yy * 5];
            atomicAdd(dst + 0, a.x); atomicAdd(dst + 1, a.y);
            atomicAdd(dst + 2, a.z); atomicAdd(dst + 3, a.w);
        }
        __syncthreads();
        #pragma unroll
        for (int v = 0; v < 2; ++v) {
            int c = t + v * 256;
            float inv = 1.0f / (cnt[c] + EPSV);
            *(float4*)&g_mean[(size_t)c * DNUM + d0] =
                make_float4(acc[c * 5 + 0] * inv, acc[c * 5 + 1] * inv,
                            acc[c * 5 + 2] * inv, acc[c * 5 + 3] * inv);
        }
    } else {
        #pragma unroll
        for (int v = 0; v < 2; ++v) {
            int c = t + v * 256;
            g_counts[c] = cnt[c];
            g_lp[c] = logf(cnt[c] + EPSV) - logtot;
        }
    }
}

// ---- G split-K partial: rows [b*64, b*64+64) of X=[z; mean], weighted ----
__global__ __launch_bounds__(256) void k_gpart(const float* __restrict__ z) {
    __shared__ float xs[64][132];
    __shared__ float ws[64];
    const int t = threadIdx.x;
    const int R0 = blockIdx.x * 64;
    #pragma unroll
    for (int v = 0; v < 8; ++v) {
        int idx = t + v * 256;
        int r = idx >> 5, f4 = idx & 31;
        int row = R0 + r;
        float4 val;
        if (row < BNUM) {
            val = ((const float4*)z)[(size_t)row * 32 + f4];
            if (f4 == 0) ws[r] = 1.0f;
        } else {
            int c = row - BNUM;
            val = ((const float4*)g_mean)[(size_t)c * 32 + f4];
            if (f4 == 0) ws[r] = -(g_counts[c] + 2.0f * EPSV);
        }
        *(float4*)&xs[r][f4 * 4] = val;
    }
    __syncthreads();
    const int tx = t & 15, ty = t >> 4;
    float acc[8][8] = {};
    #pragma unroll
    for (int s = 0; s < 64; ++s) {
        const float4* pa = (const float4*)&xs[s][ty * 8];
        const float4* pb = (const float4*)&xs[s][tx * 8];
        float w = ws[s];
        float4 t0 = pa[0], t1 = pa[1];
        float4 u0 = pb[0], u1 = pb[1];
        float va[8] = {w * t0.x, w * t0.y, w * t0.z, w * t0.w, w * t1.x, w * t1.y, w * t1.z, w * t1.w};
        float vb[8] = {u0.x, u0.y, u0.z, u0.w, u1.x, u1.y, u1.z, u1.w};
        #pragma unroll
        for (int i = 0; i < 8; ++i)
            #pragma unroll
            for (int j = 0; j < 8; ++j)
                acc[i][j] += va[i] * vb[j];
    }
    float* gp = g_Gp + (size_t)blockIdx.x * DNUM * DNUM;
    #pragma unroll
    for (int i = 0; i < 8; ++i) {
        *(float4*)(gp + (size_t)(ty * 8 + i) * DNUM + tx * 8)     = make_float4(acc[i][0], acc[i][1], acc[i][2], acc[i][3]);
        *(float4*)(gp + (size_t)(ty * 8 + i) * DNUM + tx * 8 + 4) = make_float4(acc[i][4], acc[i][5], acc[i][6], acc[i][7]);
    }
}

// ---------------- reduce 72 partials -> g_G ----------------
__global__ __launch_bounds__(256) void k_greduce() {
    int idx = blockIdx.x * 256 + threadIdx.x;   // 16384 threads
    float s = 0.0f;
    #pragma unroll
    for (int p = 0; p < GPBLK; ++p) s += g_Gp[(size_t)p * DNUM * DNUM + idx];
    g_G[idx] = s;
}

// ---- scalar register-tile Gauss-Jordan, ONE barrier per pivot (R11, 58us) ----
__global__ __launch_bounds__(256) void k_gj(float invtot2) {
    __shared__ float colu[2][128];
    __shared__ float rowu[2][128];
    __shared__ float dshs[2];
    const int tx = threadIdx.x & 15, ty = threadIdx.x >> 4;
    const int R = ty * 8, Cc = tx * 8;
    float a[8][8];
    #pragma unroll
    for (int i = 0; i < 8; ++i)
        #pragma unroll
        for (int j = 0; j < 8; ++j) {
            int gi = R + i, gj = Cc + j;
            float v = (g_G[gi * DNUM + gj] + g_G[gj * DNUM + gi]) * invtot2;
            if (gi == gj) v += EPSV;
            a[i][j] = v;
        }
    if (tx == 0) {
        #pragma unroll
        for (int i = 0; i < 8; ++i) { int gi = R + i; colu[0][gi] = (gi == 0) ? 0.f : a[i][0]; }
    }
    if (ty == 0) {
        #pragma unroll
        for (int j = 0; j < 8; ++j) { int gj = Cc + j; rowu[0][gj] = (gj == 0) ? 0.f : a[0][j]; }
    }
    if (tx == 0 && ty == 0) dshs[0] = 1.0f / a[0][0];
    __syncthreads();
    for (int kb = 0; kb < 16; ++kb) {
        #pragma unroll
        for (int ko = 0; ko < 8; ++ko) {
            const int k = kb * 8 + ko;
            const int buf = k & 1;
            const float d = dshs[buf];
            float4 c0 = *(const float4*)&colu[buf][R], c1 = *(const float4*)&colu[buf][R + 4];
            float4 r0 = *(const float4*)&rowu[buf][Cc], r1 = *(const float4*)&rowu[buf][Cc + 4];
            float cd[8] = {-d * c0.x, -d * c0.y, -d * c0.z, -d * c0.w,
                           -d * c1.x, -d * c1.y, -d * c1.z, -d * c1.w};
            float rr[8] = {r0.x, r0.y, r0.z, r0.w, r1.x, r1.y, r1.z, r1.w};
            #pragma unroll
            for (int i = 0; i < 8; ++i)
                #pragma unroll
                for (int j = 0; j < 8; ++j)
                    a[i][j] += cd[i] * rr[j];
            if (tx == kb) {
                #pragma unroll
                for (int i = 0; i < 8; ++i) { int gi = R + i; if (gi != k) a[i][ko] = cd[i]; }
            }
            if (ty == kb) {
                #pragma unroll
                for (int j = 0; j < 8; ++j) { int gj = Cc + j; if (gj != k) a[ko][j] *= d; }
                if (tx == kb) a[ko][ko] = d;
            }
            if (k < 127) {
                const int nb = buf ^ 1;
                if (ko < 7) {
                    const int kn = k + 1;
                    if (tx == kb) {
                        #pragma unroll
                        for (int i = 0; i < 8; ++i) { int gi = R + i; colu[nb][gi] = (gi == kn) ? 0.f : a[i][ko + 1]; }
                    }
                    if (ty == kb) {
                        #pragma unroll
                        for (int j = 0; j < 8; ++j) { int gj = Cc + j; rowu[nb][gj] = (gj == kn) ? 0.f : a[ko + 1][j]; }
                    }
                    if (tx == kb && ty == kb) dshs[nb] = 1.0f / a[ko + 1][ko + 1];
                } else {
                    const int kn = k + 1;
                    if (tx == kb + 1) {
                        #pragma unroll
                        for (int i = 0; i < 8; ++i) { int gi = R + i; colu[nb][gi] = (gi == kn) ? 0.f : a[i][0]; }
                    }
                    if (ty == kb + 1) {
                        #pragma unroll
                        for (int j = 0; j < 8; ++j) { int gj = Cc + j; rowu[nb][gj] = (gj == kn) ? 0.f : a[0][j]; }
                    }
                    if (tx == kb + 1 && ty == kb + 1) dshs[nb] = 1.0f / a[0][0];
                }
            }
            __syncthreads();
        }
    }
    #pragma unroll
    for (int i = 0; i < 8; ++i) {
        *(float4*)(g_P + (size_t)(R + i) * DNUM + Cc)     = make_float4(a[i][0], a[i][1], a[i][2], a[i][3]);
        *(float4*)(g_P + (size_t)(R + i) * DNUM + Cc + 4) = make_float4(a[i][4], a[i][5], a[i][6], a[i][7]);
    }
}

// ---- fused X@P row-dot kernel: blocks 0..7 mean (Pm + r), 8..71 z (q) ----
__global__ __launch_bounds__(256) void k_xpq(const float* __restrict__ z) {
    __shared__ float xs[64][132];
    __shared__ float part[64][33];
    const int t = threadIdx.x;
    const int bi = blockIdx.x;
    const bool mmode = (bi < 8);
    const float* __restrict__ X = mmode ? (const float*)g_mean : z;
    const int row0 = mmode ? bi * 64 : (bi - 8) * 64;
    #pragma unroll
    for (int v = 0; v < 8; ++v) {
        int idx = t + v * 256;
        int r = idx >> 5, f4 = idx & 31;
        float4 val = ((const float4*)X)[(size_t)(row0 + r) * 32 + f4];
        *(float4*)&xs[r][f4 * 4] = val;
    }
    __syncthreads();
    int tx = t & 31, ty = t >> 5;
    float acc[8][4] = {};
    for (int e = 0; e < DNUM; ++e) {
        float4 pv = ((const float4*)g_P)[e * 32 + tx];
        #pragma unroll
        for (int i = 0; i < 8; ++i) {
            float xv = xs[ty * 8 + i][e];
            acc[i][0] += xv * pv.x; acc[i][1] += xv * pv.y;
            acc[i][2] += xv * pv.z; acc[i][3] += xv * pv.w;
        }
    }
    #pragma unroll
    for (int i = 0; i < 8; ++i) {
        int r = ty * 8 + i;
        if (mmode)
            *(float4*)&g_Pm[(size_t)(row0 + r) * DNUM + tx * 4] =
                make_float4(acc[i][0], acc[i][1], acc[i][2], acc[i][3]);
        part[r][tx] = acc[i][0] * xs[r][tx * 4 + 0] + acc[i][1] * xs[r][tx * 4 + 1]
                    + acc[i][2] * xs[r][tx * 4 + 2] + acc[i][3] * xs[r][tx * 4 + 3];
    }
    __syncthreads();
    if (t < 64) {
        float s = 0.f;
        #pragma unroll
        for (int x = 0; x < 32; ++x) s += part[t][x];
        if (mmode) g_r[row0 + t] = s;
        else       g_q[row0 + t] = s;
    }
}

// ---------------- out[b][c] = lp[c] - 0.5*q_b - 0.5*r_c + z_b . Pm_c ----------------
__global__ __launch_bounds__(256) void k_out(const float* __restrict__ z, float* __restrict__ out) {
    __shared__ float zs[64][65];
    __shared__ float ps[64][65];
    int t = threadIdx.x;
    int m0 = blockIdx.y * 64;      // sample rows
    int c0 = blockIdx.x * 64;      // class cols
    int tx = t & 15, ty = t >> 4;
    float acc[4][4] = {};
    for (int kc = 0; kc < 2; ++kc) {
        #pragma unroll
        for (int v = 0; v < 4; ++v) {
            int idx = t + v * 256;
            int r = idx >> 4, f4 = idx & 15;
            float4 zv = ((const float4*)z)[(size_t)(m0 + r) * 32 + kc * 16 + f4];
            zs[r][f4 * 4 + 0] = zv.x; zs[r][f4 * 4 + 1] = zv.y;
            zs[r][f4 * 4 + 2] = zv.z; zs[r][f4 * 4 + 3] = zv.w;
            float4 pv = ((const float4*)g_Pm)[(size_t)(c0 + r) * 32 + kc * 16 + f4];
            ps[r][f4 * 4 + 0] = pv.x; ps[r][f4 * 4 + 1] = pv.y;
            ps[r][f4 * 4 + 2] = pv.z; ps[r][f4 * 4 + 3] = pv.w;
        }
        __syncthreads();
        #pragma unroll 8
        for (int kk = 0; kk < 64; ++kk) {
            float za[4], pb[4];
            #pragma unroll
            for (int i = 0; i < 4; ++i) za[i] = zs[ty * 4 + i][kk];
            #pragma unroll
            for (int j = 0; j < 4; ++j) pb[j] = ps[tx * 4 + j][kk];
            #pragma unroll
            for (int i = 0; i < 4; ++i)
                #pragma unroll
                for (int j = 0; j < 4; ++j)
                    acc[i][j] += za[i] * pb[j];
        }
        __syncthreads();
    }
    int cbase = c0 + tx * 4;
    float4 lp4 = *(const float4*)(g_lp + cbase);
    float4 rv4 = *(const float4*)(g_r + cbase);
    #pragma unroll
    for (int i = 0; i < 4; ++i) {
        int row = m0 + ty * 4 + i;
        float qv = g_q[row];
        float4 o;
        o.x = acc[i][0] + lp4.x - 0.5f * (qv + rv4.x);
        o.y = acc[i][1] + lp4.y - 0.5f * (qv + rv4.y);
        o.z = acc[i][2] + lp4.z - 0.5f * (qv + rv4.z);
        o.w = acc[i][3] + lp4.w - 0.5f * (qv + rv4.w);
        *(float4*)&out[(size_t)row * CNUM + cbase] = o;
    }
}

extern "C" void kernel_launch(void* const* d_in, const int* in_sizes, int n_in,
                              void* d_out, int out_size, void* d_ws, size_t ws_size,
                              hipStream_t stream) {
    const float* z = (const float*)d_in[0];
    const int* y = (const int*)d_in[1];
    float* out = (float*)d_out;
    const int B = in_sizes[0] / DNUM;                 // 4096
    const float total = (float)B + (float)CNUM * EPSV;
    const float logtot = logf(total);

    k_csum<<<33, 256, 0, stream>>>(z, y, logtot);
    k_gpart<<<GPBLK, 256, 0, stream>>>(z);
    k_greduce<<<DNUM * DNUM / 256, 256, 0, stream>>>();
    k_gj<<<1, 256, 0, stream>>>(0.5f / total);
    k_xpq<<<GPBLK, 256, 0, stream>>>(z);
    k_out<<<dim3(CNUM / 64, B / 64), 256, 0, stream>>>(z, out);
}

// Round 15
// 183.822 us; speedup vs baseline: 2.1005x; 1.0125x over previous
//
#include <hip/hip_runtime.h>
#include <cmath>

#define CNUM 512
#define DNUM 128
#define BNUM 4096
#define EPSV 1e-5f
#define GPBLK 72            // (4096 + 512) / 64 split-K partial blocks

// ---- all intermediates in device globals: no d_ws dependence at all ----
__device__ float g_counts[CNUM];
__device__ float g_mean[CNUM * DNUM];
__device__ float g_lp[CNUM];
__device__ float g_G[DNUM * DNUM];
__device__ float g_Gp[GPBLK * DNUM * DNUM];   // split-K partials, 4.7 MB
__device__ float g_P[DNUM * DNUM];
__device__ float g_Pm[CNUM * DNUM];
__device__ float g_r[CNUM];
__device__ float g_q[BNUM];

// ---- class sums + counts + mean + logprior (stride-5 LDS, R14: conflict-free) ----
__global__ __launch_bounds__(256) void k_csum(const float* __restrict__ z, const int* __restrict__ y,
                                              float logtot) {
    const int t = threadIdx.x;
    const int bi = blockIdx.x;
    __shared__ float cnt[CNUM];
    cnt[t] = 0.0f; cnt[t + 256] = 0.0f;
    __syncthreads();
    #pragma unroll
    for (int i = 0; i < 16; ++i) atomicAdd(&cnt[y[i * 256 + t]], 1.0f);
    __syncthreads();
    if (bi < 32) {
        __shared__ float acc[CNUM * 5];       // 10 KB, stride-5 padded
        #pragma unroll
        for (int v = 0; v < 10; ++v) acc[t + v * 256] = 0.0f;
        __syncthreads();
        const int d0 = bi * 4;
        #pragma unroll
        for (int i = 0; i < 16; ++i) {
            int s = i * 256 + t;
            int yy = y[s];
            float4 a = *(const float4*)(z + (size_t)s * DNUM + d0);
            float* dst = &acc[yy * 5];
            atomicAdd(dst + 0, a.x); atomicAdd(dst + 1, a.y);
            atomicAdd(dst + 2, a.z); atomicAdd(dst + 3, a.w);
        }
        __syncthreads();
        #pragma unroll
        for (int v = 0; v < 2; ++v) {
            int c = t + v * 256;
            float inv = 1.0f / (cnt[c] + EPSV);
            *(float4*)&g_mean[(size_t)c * DNUM + d0] =
                make_float4(acc[c * 5 + 0] * inv, acc[c * 5 + 1] * inv,
                            acc[c * 5 + 2] * inv, acc[c * 5 + 3] * inv);
        }
    } else {
        #pragma unroll
        for (int v = 0; v < 2; ++v) {
            int c = t + v * 256;
            g_counts[c] = cnt[c];
            g_lp[c] = logf(cnt[c] + EPSV) - logtot;
        }
    }
}

// ---- G split-K partial: rows [b*64, b*64+64) of X=[z; mean], weighted ----
__global__ __launch_bounds__(256) void k_gpart(const float* __restrict__ z) {
    __shared__ float xs[64][132];
    __shared__ float ws[64];
    const int t = threadIdx.x;
    const int R0 = blockIdx.x * 64;
    #pragma unroll
    for (int v = 0; v < 8; ++v) {
        int idx = t + v * 256;
        int r = idx >> 5, f4 = idx & 31;
        int row = R0 + r;
        float4 val;
        if (row < BNUM) {
            val = ((const float4*)z)[(size_t)row * 32 + f4];
            if (f4 == 0) ws[r] = 1.0f;
        } else {
            int c = row - BNUM;
            val = ((const float4*)g_mean)[(size_t)c * 32 + f4];
            if (f4 == 0) ws[r] = -(g_counts[c] + 2.0f * EPSV);
        }
        *(float4*)&xs[r][f4 * 4] = val;
    }
    __syncthreads();
    const int tx = t & 15, ty = t >> 4;
    float acc[8][8] = {};
    #pragma unroll
    for (int s = 0; s < 64; ++s) {
        const float4* pa = (const float4*)&xs[s][ty * 8];
        const float4* pb = (const float4*)&xs[s][tx * 8];
        float w = ws[s];
        float4 t0 = pa[0], t1 = pa[1];
        float4 u0 = pb[0], u1 = pb[1];
        float va[8] = {w * t0.x, w * t0.y, w * t0.z, w * t0.w, w * t1.x, w * t1.y, w * t1.z, w * t1.w};
        float vb[8] = {u0.x, u0.y, u0.z, u0.w, u1.x, u1.y, u1.z, u1.w};
        #pragma unroll
        for (int i = 0; i < 8; ++i)
            #pragma unroll
            for (int j = 0; j < 8; ++j)
                acc[i][j] += va[i] * vb[j];
    }
    float* gp = g_Gp + (size_t)blockIdx.x * DNUM * DNUM;
    #pragma unroll
    for (int i = 0; i < 8; ++i) {
        *(float4*)(gp + (size_t)(ty * 8 + i) * DNUM + tx * 8)     = make_float4(acc[i][0], acc[i][1], acc[i][2], acc[i][3]);
        *(float4*)(gp + (size_t)(ty * 8 + i) * DNUM + tx * 8 + 4) = make_float4(acc[i][4], acc[i][5], acc[i][6], acc[i][7]);
    }
}

// ---------------- reduce 72 partials -> g_G ----------------
__global__ __launch_bounds__(256) void k_greduce() {
    int idx = blockIdx.x * 256 + threadIdx.x;   // 16384 threads
    float s = 0.0f;
    #pragma unroll
    for (int p = 0; p < GPBLK; ++p) s += g_Gp[(size_t)p * DNUM * DNUM + idx];
    g_G[idx] = s;
}

// ---- SWEEP-symmetric dual-pivot register-tile Gauss-Jordan ----
// SPD sweep invariant: M_k = [[B^-1, B^-1 C],[-(B^-1 C)^T, Schur]] so
// row_k[j] = +col_k[j] (j>k) / -col_k[j] (j<k): publish COLUMN + d only.
// Two scalar pivots per barrier: (v_k,d_k) exact + (v_{k+1},p_{k+1}) at
// state A_k; consumers correct v'_{k+1}[i] = v_{k+1}[i] - d*v_k[i]*vk1
// (specials i==k -> d*vk1, i==k+1 -> 0), d' = 1/(p - d*vk1^2).
// 65 barriers vs 129; no one-thread serial work (R8/R10 lesson).
__global__ __launch_bounds__(256) void k_gj(float invtot2) {
    __shared__ float va[2][128];   // even pivot column (pivot slot zeroed)
    __shared__ float vb[2][128];   // odd pivot column (raw, state = even base)
    __shared__ float dp[2][2];     // {d_even, p_odd_raw}
    const int tx = threadIdx.x & 15, ty = threadIdx.x >> 4;
    const int R = ty * 8, Cc = tx * 8;
    float a[8][8];
    #pragma unroll
    for (int i = 0; i < 8; ++i)
        #pragma unroll
        for (int j = 0; j < 8; ++j) {
            int gi = R + i, gj = Cc + j;
            float v = (g_G[gi * DNUM + gj] + g_G[gj * DNUM + gi]) * invtot2;
            if (gi == gj) v += EPSV;
            a[i][j] = v;
        }
    if (tx == 0) {
        #pragma unroll
        for (int i = 0; i < 8; ++i) {
            int gi = R + i;
            va[0][gi] = (gi == 0) ? 0.f : a[i][0];
            vb[0][gi] = a[i][1];
        }
    }
    if (tx == 0 && ty == 0) { dp[0][0] = 1.0f / a[0][0]; dp[0][1] = a[1][1]; }
    __syncthreads();
    for (int kb = 0; kb < 16; ++kb) {
        #pragma unroll
        for (int kp = 0; kp < 8; kp += 2) {
            const int k  = kb * 8 + kp;
            const int k2 = k + 1;
            const int s  = (k >> 1) & 1;
            const float d   = dp[s][0];
            const float p   = dp[s][1];
            const float vk1 = va[s][k2];
            float4 ar0 = *(const float4*)&va[s][R],  ar1 = *(const float4*)&va[s][R + 4];
            float4 br0 = *(const float4*)&vb[s][R],  br1 = *(const float4*)&vb[s][R + 4];
            float4 ac0 = *(const float4*)&va[s][Cc], ac1 = *(const float4*)&va[s][Cc + 4];
            float4 bc0 = *(const float4*)&vb[s][Cc], bc1 = *(const float4*)&vb[s][Cc + 4];
            float var_[8] = {ar0.x, ar0.y, ar0.z, ar0.w, ar1.x, ar1.y, ar1.z, ar1.w};
            float vbr_[8] = {br0.x, br0.y, br0.z, br0.w, br1.x, br1.y, br1.z, br1.w};
            float vac_[8] = {ac0.x, ac0.y, ac0.z, ac0.w, ac1.x, ac1.y, ac1.z, ac1.w};
            float vbc_[8] = {bc0.x, bc0.y, bc0.z, bc0.w, bc1.x, bc1.y, bc1.z, bc1.w};
            const float dn = 1.0f / (p - d * vk1 * vk1);      // d' for pivot k+1
            // pivot-k vectors: cd at rows, signed row at cols (va[k]=0 masks both)
            float cd[8], rr[8];
            #pragma unroll
            for (int i = 0; i < 8; ++i) cd[i] = -d * var_[i];
            #pragma unroll
            for (int j = 0; j < 8; ++j) rr[j] = (Cc + j > k) ? vac_[j] : -vac_[j];
            #pragma unroll
            for (int i = 0; i < 8; ++i)
                #pragma unroll
                for (int j = 0; j < 8; ++j)
                    a[i][j] += cd[i] * rr[j];
            if (tx == kb) {
                #pragma unroll
                for (int i = 0; i < 8; ++i) { int gi = R + i; if (gi != k) a[i][kp] = cd[i]; }
            }
            if (ty == kb) {
                #pragma unroll
                for (int j = 0; j < 8; ++j) { int gj = Cc + j; if (gj != k) a[kp][j] *= d; }
                if (tx == kb) a[kp][kp] = d;
            }
            // corrected pivot-(k+1) column at rows and cols
            float vpr[8], vpc[8];
            #pragma unroll
            for (int i = 0; i < 8; ++i) {
                int gi = R + i;
                float v = vbr_[i] + cd[i] * vk1;
                if (gi == k)  v = d * vk1;
                if (gi == k2) v = 0.f;
                vpr[i] = v;
            }
            #pragma unroll
            for (int j = 0; j < 8; ++j) {
                int gj = Cc + j;
                float v = vbc_[j] - d * vac_[j] * vk1;
                if (gj == k)  v = d * vk1;
                if (gj == k2) v = 0.f;
                vpc[j] = v;
            }
            float cd2[8], rr2[8];
            #pragma unroll
            for (int i = 0; i < 8; ++i) cd2[i] = -dn * vpr[i];
            #pragma unroll
            for (int j = 0; j < 8; ++j) rr2[j] = (Cc + j > k2) ? vpc[j] : -vpc[j];
            #pragma unroll
            for (int i = 0; i < 8; ++i)
                #pragma unroll
                for (int j = 0; j < 8; ++j)
                    a[i][j] += cd2[i] * rr2[j];
            if (tx == kb) {
                #pragma unroll
                for (int i = 0; i < 8; ++i) { int gi = R + i; if (gi != k2) a[i][kp + 1] = cd2[i]; }
            }
            if (ty == kb) {
                #pragma unroll
                for (int j = 0; j < 8; ++j) { int gj = Cc + j; if (gj != k2) a[kp + 1][j] *= dn; }
                if (tx == kb) a[kp + 1][kp + 1] = dn;
            }
            // publish next pair (k+2, k+3) at full A_{k+2} state
            if (k2 < 127) {
                const int ns = s ^ 1;
                if (kp < 6) {
                    if (tx == kb) {
                        #pragma unroll
                        for (int i = 0; i < 8; ++i) {
                            int gi = R + i;
                            va[ns][gi] = (gi == k + 2) ? 0.f : a[i][kp + 2];
                            vb[ns][gi] = a[i][kp + 3];
                        }
                    }
                    if (tx == kb && ty == kb) { dp[ns][0] = 1.0f / a[kp + 2][kp + 2]; dp[ns][1] = a[kp + 3][kp + 3]; }
                } else {
                    if (tx == kb + 1) {
                        #pragma unroll
                        for (int i = 0; i < 8; ++i) {
                            int gi = R + i;
                            va[ns][gi] = (gi == k + 2) ? 0.f : a[i][0];
                            vb[ns][gi] = a[i][1];
                        }
                    }
                    if (tx == kb + 1 && ty == kb + 1) { dp[ns][0] = 1.0f / a[0][0]; dp[ns][1] = a[1][1]; }
                }
            }
            __syncthreads();
        }
    }
    #pragma unroll
    for (int i = 0; i < 8; ++i) {
        *(float4*)(g_P + (size_t)(R + i) * DNUM + Cc)     = make_float4(a[i][0], a[i][1], a[i][2], a[i][3]);
        *(float4*)(g_P + (size_t)(R + i) * DNUM + Cc + 4) = make_float4(a[i][4], a[i][5], a[i][6], a[i][7]);
    }
}

// ---- fused X@P row-dot kernel: blocks 0..7 mean (Pm + r), 8..71 z (q) ----
__global__ __launch_bounds__(256) void k_xpq(const float* __restrict__ z) {
    __shared__ float xs[64][132];
    __shared__ float part[64][33];
    const int t = threadIdx.x;
    const int bi = blockIdx.x;
    const bool mmode = (bi < 8);
    const float* __restrict__ X = mmode ? (const float*)g_mean : z;
    const int row0 = mmode ? bi * 64 : (bi - 8) * 64;
    #pragma unroll
    for (int v = 0; v < 8; ++v) {
        int idx = t + v * 256;
        int r = idx >> 5, f4 = idx & 31;
        float4 val = ((const float4*)X)[(size_t)(row0 + r) * 32 + f4];
        *(float4*)&xs[r][f4 * 4] = val;
    }
    __syncthreads();
    int tx = t & 31, ty = t >> 5;
    float acc[8][4] = {};
    for (int e = 0; e < DNUM; ++e) {
        float4 pv = ((const float4*)g_P)[e * 32 + tx];
        #pragma unroll
        for (int i = 0; i < 8; ++i) {
            float xv = xs[ty * 8 + i][e];
            acc[i][0] += xv * pv.x; acc[i][1] += xv * pv.y;
            acc[i][2] += xv * pv.z; acc[i][3] += xv * pv.w;
        }
    }
    #pragma unroll
    for (int i = 0; i < 8; ++i) {
        int r = ty * 8 + i;
        if (mmode)
            *(float4*)&g_Pm[(size_t)(row0 + r) * DNUM + tx * 4] =
                make_float4(acc[i][0], acc[i][1], acc[i][2], acc[i][3]);
        part[r][tx] = acc[i][0] * xs[r][tx * 4 + 0] + acc[i][1] * xs[r][tx * 4 + 1]
                    + acc[i][2] * xs[r][tx * 4 + 2] + acc[i][3] * xs[r][tx * 4 + 3];
    }
    __syncthreads();
    if (t < 64) {
        float s = 0.f;
        #pragma unroll
        for (int x = 0; x < 32; ++x) s += part[t][x];
        if (mmode) g_r[row0 + t] = s;
        else       g_q[row0 + t] = s;
    }
}

// ---------------- out[b][c] = lp[c] - 0.5*q_b - 0.5*r_c + z_b . Pm_c ----------------
__global__ __launch_bounds__(256) void k_out(const float* __restrict__ z, float* __restrict__ out) {
    __shared__ float zs[64][65];
    __shared__ float ps[64][65];
    int t = threadIdx.x;
    int m0 = blockIdx.y * 64;      // sample rows
    int c0 = blockIdx.x * 64;      // class cols
    int tx = t & 15, ty = t >> 4;
    float acc[4][4] = {};
    for (int kc = 0; kc < 2; ++kc) {
        #pragma unroll
        for (int v = 0; v < 4; ++v) {
            int idx = t + v * 256;
            int r = idx >> 4, f4 = idx & 15;
            float4 zv = ((const float4*)z)[(size_t)(m0 + r) * 32 + kc * 16 + f4];
            zs[r][f4 * 4 + 0] = zv.x; zs[r][f4 * 4 + 1] = zv.y;
            zs[r][f4 * 4 + 2] = zv.z; zs[r][f4 * 4 + 3] = zv.w;
            float4 pv = ((const float4*)g_Pm)[(size_t)(c0 + r) * 32 + kc * 16 + f4];
            ps[r][f4 * 4 + 0] = pv.x; ps[r][f4 * 4 + 1] = pv.y;
            ps[r][f4 * 4 + 2] = pv.z; ps[r][f4 * 4 + 3] = pv.w;
        }
        __syncthreads();
        #pragma unroll 8
        for (int kk = 0; kk < 64; ++kk) {
            float za[4], pb[4];
            #pragma unroll
            for (int i = 0; i < 4; ++i) za[i] = zs[ty * 4 + i][kk];
            #pragma unroll
            for (int j = 0; j < 4; ++j) pb[j] = ps[tx * 4 + j][kk];
            #pragma unroll
            for (int i = 0; i < 4; ++i)
                #pragma unroll
                for (int j = 0; j < 4; ++j)
                    acc[i][j] += za[i] * pb[j];
        }
        __syncthreads();
    }
    int cbase = c0 + tx * 4;
    float4 lp4 = *(const float4*)(g_lp + cbase);
    float4 rv4 = *(const float4*)(g_r + cbase);
    #pragma unroll
    for (int i = 0; i < 4; ++i) {
        int row = m0 + ty * 4 + i;
        float qv = g_q[row];
        float4 o;
        o.x = acc[i][0] + lp4.x - 0.5f * (qv + rv4.x);
        o.y = acc[i][1] + lp4.y - 0.5f * (qv + rv4.y);
        o.z = acc[i][2] + lp4.z - 0.5f * (qv + rv4.z);
        o.w = acc[i][3] + lp4.w - 0.5f * (qv + rv4.w);
        *(float4*)&out[(size_t)row * CNUM + cbase] = o;
    }
}

extern "C" void kernel_launch(void* const* d_in, const int* in_sizes, int n_in,
                              void* d_out, int out_size, void* d_ws, size_t ws_size,
                              hipStream_t stream) {
    const float* z = (const float*)d_in[0];
    const int* y = (const int*)d_in[1];
    float* out = (float*)d_out;
    const int B = in_sizes[0] / DNUM;                 // 4096
    const float total = (float)B + (float)CNUM * EPSV;
    const float logtot = logf(total);

    k_csum<<<33, 256, 0, stream>>>(z, y, logtot);
    k_gpart<<<GPBLK, 256, 0, stream>>>(z);
    k_greduce<<<DNUM * DNUM / 256, 256, 0, stream>>>();
    k_gj<<<1, 256, 0, stream>>>(0.5f / total);
    k_xpq<<<GPBLK, 256, 0, stream>>>(z);
    k_out<<<dim3(CNUM / 64, B / 64), 256, 0, stream>>>(z, out);
}